// Round 13
// baseline (167.661 us; speedup 1.0000x reference)
//
#include <hip/hip_runtime.h>
#include <hip/hip_bf16.h>
#include <stdint.h>

// Problem constants (from reference setup_inputs)
#define BB 64
#define SS 2048
#define DD 6
#define HH 8
#define NCH 512           // chains = B*H
#define CHUNKS 256        // chunks per chain
#define LCH 8             // steps per chunk = SS/CHUNKS

typedef unsigned short ushort_t;
typedef __attribute__((ext_vector_type(8))) __bf16 bf16x8;
typedef __attribute__((ext_vector_type(4))) float f32x4;

// ---------------- compile-time Cayley sign table (Cl(4,1)) ----------------
struct SignTab { float s[32][32]; };

constexpr int popc5_c(unsigned v) {
    int c = 0;
    for (int i = 0; i < 5; ++i) c += (v >> i) & 1u;
    return c;
}

constexpr SignTab make_signs() {
    SignTab t{};
    for (int a = 0; a < 32; ++a) {
        for (int b = 0; b < 32; ++b) {
            int cnt = 0;
            unsigned aa = ((unsigned)a) >> 1;
            while (aa) { cnt += popc5_c(aa & (unsigned)b); aa >>= 1; }
            if ((a & b) & 16) cnt += 1;   // metric: e5^2 = -1 (bit 4)
            t.s[a][b] = (cnt & 1) ? -1.0f : 1.0f;
        }
    }
    return t;
}

constexpr SignTab SGN = make_signs();

// out = a * b  (geometric product, a is LEFT operand: out_k = sum_i s(i,i^k) a_i b_{i^k})
__device__ __forceinline__ void gp_cl41(const float* __restrict__ a,
                                        const float* __restrict__ b,
                                        float* __restrict__ o) {
#pragma unroll
    for (int k = 0; k < 32; ++k) o[k] = 0.0f;
#pragma unroll
    for (int i = 0; i < 32; ++i) {
#pragma unroll
        for (int k = 0; k < 32; ++k) {
            o[k] = fmaf(SGN.s[i][i ^ k] * a[i], b[i ^ k], o[k]);
        }
    }
}

__device__ __forceinline__ float sumsq32(const float* v) {
    float n0 = 0.f, n1 = 0.f, n2 = 0.f, n3 = 0.f;
#pragma unroll
    for (int k = 0; k < 32; k += 4) {
        n0 = fmaf(v[k+0], v[k+0], n0);
        n1 = fmaf(v[k+1], v[k+1], n1);
        n2 = fmaf(v[k+2], v[k+2], n2);
        n3 = fmaf(v[k+3], v[k+3], n3);
    }
    return (n0 + n1) + (n2 + n3);
}

__device__ __forceinline__ float rsq(float n) {
    return __builtin_amdgcn_rsqf(n);   // v_rsq_f32, scale-equivalent
}

// HW bf16 pack: (__bf16) casts are RNE on gfx950; compiler emits
// v_cvt_pk_bf16_f32 for the pair (round-10 win vs bit-math).
__device__ __forceinline__ uint32_t pack2bf(float a, float b) {
    union { __bf16 h[2]; uint32_t u; } t;
    t.h[0] = (__bf16)a; t.h[1] = (__bf16)b;
    return t.u;
}
__device__ __forceinline__ ushort_t bf1(float a) {
    union { __bf16 h; ushort_t u; } t;
    t.h = (__bf16)a;
    return t.u;
}

// SINGLE delta build — k_scan form (round 11, best measured: VGPR 180).
// All lanes share one h, so every sW read is a same-address broadcast (free);
// round-12 showed the paired form's +76 VGPR live-set costs more than the
// "saved" broadcast reads are worth.
__device__ __forceinline__ void make_delta1(const float4* __restrict__ sW,
                                            const float* __restrict__ x6,
                                            float* __restrict__ dl) {
#pragma unroll
    for (int j4 = 0; j4 < 8; ++j4) {
        float4 bv = sW[48 + j4];
        dl[4*j4+0] = bv.x; dl[4*j4+1] = bv.y; dl[4*j4+2] = bv.z; dl[4*j4+3] = bv.w;
    }
#pragma unroll
    for (int d = 0; d < 6; ++d) {
        float a = x6[d];
#pragma unroll
        for (int j4 = 0; j4 < 8; ++j4) {
            float4 w = sW[d * 8 + j4];
            dl[4*j4+0] = fmaf(a, w.x, dl[4*j4+0]);
            dl[4*j4+1] = fmaf(a, w.y, dl[4*j4+1]);
            dl[4*j4+2] = fmaf(a, w.z, dl[4*j4+2]);
            dl[4*j4+3] = fmaf(a, w.w, dl[4*j4+3]);
        }
    }
    dl[0] += 1.0f;
}

// PAIRED delta build — k_chain only (per-lane h differs; pairing halves REAL
// LDS traffic there).
__device__ __forceinline__ void make_delta2(const float4* __restrict__ sW,
                                            const float* __restrict__ xv,
                                            float* __restrict__ dl0,
                                            float* __restrict__ dl1) {
#pragma unroll
    for (int j4 = 0; j4 < 8; ++j4) {
        float4 bv = sW[48 + j4];
        dl0[4*j4+0] = bv.x; dl0[4*j4+1] = bv.y; dl0[4*j4+2] = bv.z; dl0[4*j4+3] = bv.w;
        dl1[4*j4+0] = bv.x; dl1[4*j4+1] = bv.y; dl1[4*j4+2] = bv.z; dl1[4*j4+3] = bv.w;
    }
#pragma unroll
    for (int d = 0; d < 6; ++d) {
        float a0 = xv[d], a1 = xv[6 + d];
#pragma unroll
        for (int j4 = 0; j4 < 8; ++j4) {
            float4 w = sW[d * 8 + j4];
            dl0[4*j4+0] = fmaf(a0, w.x, dl0[4*j4+0]);
            dl0[4*j4+1] = fmaf(a0, w.y, dl0[4*j4+1]);
            dl0[4*j4+2] = fmaf(a0, w.z, dl0[4*j4+2]);
            dl0[4*j4+3] = fmaf(a0, w.w, dl0[4*j4+3]);
            dl1[4*j4+0] = fmaf(a1, w.x, dl1[4*j4+0]);
            dl1[4*j4+1] = fmaf(a1, w.y, dl1[4*j4+1]);
            dl1[4*j4+2] = fmaf(a1, w.z, dl1[4*j4+2]);
            dl1[4*j4+3] = fmaf(a1, w.w, dl1[4*j4+3]);
        }
    }
    dl0[0] += 1.0f;
    dl1[0] += 1.0f;
}

__device__ __forceinline__ void loadx6(const float* __restrict__ xr, float* __restrict__ xv) {
    const float2* xp = (const float2*)xr;   // 24B-multiple offsets -> 8B aligned
#pragma unroll
    for (int m = 0; m < 3; ++m) {
        float2 t2 = xp[m];
        xv[2*m] = t2.x; xv[2*m+1] = t2.y;
    }
}

__device__ __forceinline__ void loadx12(const float* __restrict__ xr, float* __restrict__ xv) {
    const float4* xp = (const float4*)xr;
#pragma unroll
    for (int m = 0; m < 3; ++m) {
        float4 t4 = xp[m];
        xv[4*m] = t4.x; xv[4*m+1] = t4.y; xv[4*m+2] = t4.z; xv[4*m+3] = t4.w;
    }
}

// ---------------- K_A: fused chunk totals + Kogge-Stone scan -> carries ----------------
// Round-11 body (best measured 66.7us, VGPR 180) + two latency fixes:
//  (1) XCD-aware chain remap: blockIdx&7 selects the XCD (dispatch heuristic);
//      assign b in [8*xcd, 8*xcd+8) so all 8 h-chains of a b share one XCD's
//      L2 -> x fetched once per XCD instead of 8x across XCDs (round-12 FETCH
//      was 12.5MB vs 3.2MB unique). Bijective: 512 = 8 xcd * 64 slot.
//  (2) one-ahead x prefetch into named regs (compile-time indices, rule #20):
//      the unroll-1 loop can't hoist loads across the backedge, so each step's
//      L3-latency was exposed; prefetch hides it under the ~1500-cyc GP.
// Round-8 lesson: forced VGPR caps spill catastrophically -> (256,1) only.
// Round-9 lesson: no fusion with phase 2 (cross-XCD L2 non-coherence on Ebuf).
__global__ __launch_bounds__(256, 1) void k_scan(
        const float* __restrict__ x, const float* __restrict__ W_in,
        const float* __restrict__ b_in, float* __restrict__ Ebuf) {
    __shared__ float4 sW4[57];          // this chain's h-slice of W_in + bias
    __shared__ float sT[2][CHUNKS][36]; // 72 KB double-buffered scan array

    // XCD-aware remap (bijective over 512)
    int xcd  = blockIdx.x & 7;
    int slot = blockIdx.x >> 3;         // 0..63
    int b = (xcd << 3) | (slot >> 3);   // all 8 h of this b share xcd
    int h = slot & 7;
    int chain = b * 8 + h;              // logical chain for Ebuf addressing
    int c = threadIdx.x;                // chunk 0..255

    if (c < 56) {
        float4 v;
        if (c < 48) {
            int d = c / 8, j4 = c % 8;
            const float* p = W_in + d * 256 + h * 32 + 4 * j4;
            v = make_float4(p[0], p[1], p[2], p[3]);
        } else {
            const float* p = b_in + h * 32 + 4 * (c - 48);
            v = make_float4(p[0], p[1], p[2], p[3]);
        }
        sW4[c] = v;
    }
    __syncthreads();

    // ---- phase 1: chunk total, ONE textual GP, one-ahead x prefetch ----
    const float* xrow = x + ((size_t)b * SS + (size_t)c * LCH) * DD;  // 48 floats
    float P[32], O[32], dl[32];
    float xc[6], xn[6];
    loadx6(xrow, xc);
    make_delta1(sW4, xc, P);             // psi after t=0 == delta0 (GP folded)
    loadx6(xrow + 6, xc);                // x for t=1
#pragma unroll 1
    for (int t = 1; t < 8; ++t) {
        if (t < 7) loadx6(xrow + 6 * (t + 1), xn);   // prefetch next step
        make_delta1(sW4, xc, dl);
        gp_cl41(dl, P, O);               // textual GP copy #1
#pragma unroll
        for (int k = 0; k < 32; ++k) P[k] = O[k];
#pragma unroll
        for (int d = 0; d < 6; ++d) xc[d] = xn[d];
    }

    // normalized chunk total -> v, sT[0]
    float v[32];
    {
        float inv = rsq(sumsq32(P));
#pragma unroll
        for (int k = 0; k < 32; ++k) v[k] = P[k] * inv;
#pragma unroll
        for (int m = 0; m < 8; ++m)
            *(float4*)&sT[0][c][4*m] = make_float4(v[4*m], v[4*m+1], v[4*m+2], v[4*m+3]);
    }
    __syncthreads();

    // ---- phase 2: merged KS rounds rr=0..7 (off=1..128), ONE textual GP ----
    // Double-buffered: read sT[rr&1][c-off], write sT[(rr+1)&1][c] (ALL threads
    // store: propagation). Final round (rr=7): no store, no barrier.
    // Norm every other round (positive rescale -> scale-equivalent).
#pragma unroll 1
    for (int rr = 0; rr < 8; ++rr) {
        int off = 1 << rr;
        bool act = (c >= off);
        if (act) {
            float w[32];
#pragma unroll
            for (int m = 0; m < 8; ++m) {
                float4 t4 = *(const float4*)&sT[rr & 1][c - off][4*m];
                w[4*m] = t4.x; w[4*m+1] = t4.y; w[4*m+2] = t4.z; w[4*m+3] = t4.w;
            }
            gp_cl41(v, w, O);            // textual GP copy #2 (v newer -> left)
            if (rr & 1) {
                float inv = rsq(sumsq32(O));
#pragma unroll
                for (int k = 0; k < 32; ++k) v[k] = O[k] * inv;
            } else {
#pragma unroll
                for (int k = 0; k < 32; ++k) v[k] = O[k];
            }
        }
        if (rr < 7) {
#pragma unroll
            for (int m = 0; m < 8; ++m)
                *(float4*)&sT[(rr + 1) & 1][c][4*m] =
                    make_float4(v[4*m], v[4*m+1], v[4*m+2], v[4*m+3]);
            __syncthreads();
        }
    }

    // exclusive carries: E_0 = identity, E_{c+1} = normalize(inclusive_c)
    float* dst = Ebuf + (size_t)chain * CHUNKS * 32;
    if (c == 0) {
        *(float4*)dst = make_float4(1.f, 0.f, 0.f, 0.f);
#pragma unroll
        for (int m = 1; m < 8; ++m) *(float4*)(dst + 4*m) = make_float4(0.f, 0.f, 0.f, 0.f);
    }
    if (c < CHUNKS - 1) {
        float inv = rsq(sumsq32(v));
        float* d2 = dst + (size_t)(c + 1) * 32;
#pragma unroll
        for (int m = 0; m < 8; ++m)
            *(float4*)(d2 + 4*m) = make_float4(v[4*m] * inv, v[4*m+1] * inv,
                                               v[4*m+2] * inv, v[4*m+3] * inv);
    }
}

// ---------------- K_B: chain-from-carry + MFMA projection + norm ----------------
// (FROZEN round-10 body: fence-free wave-private psiT, setprio around MFMA,
// HW v_cvt_pk_bf16_f32 packs. No x duplication across blocks here -> no remap.)
__global__ __launch_bounds__(256, 1) void k_chain_proj(
        const float* __restrict__ x, const float* __restrict__ W_in,
        const float* __restrict__ b_in, const float* __restrict__ Ebuf,
        const float* __restrict__ W_out, const float* __restrict__ b_out,
        float* __restrict__ out) {
    __shared__ float4 sW4[8][57];           // 7.3 KB  W_in slices + bias
    __shared__ float sX[1536];              // 6 KB    256 s-rows x 6 floats
    __shared__ ushort_t Wt[32 * 256];       // 16 KB   W_out^T bf16, swizzled [n][k]
    __shared__ ushort_t psiT[4 * 16 * 256]; // 32 KB   per-wave 16x256 tiles, swizzled

    int tid = threadIdx.x;
    int wv = tid >> 6, lane = tid & 63;
    int b = blockIdx.x >> 3, gq = blockIdx.x & 7;
    int grp = gq * 4 + wv;
    int c0 = grp * 8;
    int cl = lane >> 3, h = lane & 7;       // chain-phase roles
    int q = lane >> 4, n0 = lane & 15;      // MFMA-phase roles

    // carry load early (hide HBM latency under staging)
    float4 pv[8];
    {
        const float4* ep = (const float4*)(Ebuf +
                (((size_t)b * HH + h) * CHUNKS + (c0 + cl)) * 32);
#pragma unroll
        for (int m = 0; m < 8; ++m) pv[m] = ep[m];
    }

    // stage W_in/b_in (448 float4, shared by all 4 waves)
    for (int idx = tid; idx < 448; idx += 256) {
        int hh = idx / 56, r = idx % 56;
        float4 v;
        if (r < 48) {
            int d = r / 8, j4 = r % 8;
            const float* p = W_in + d * 256 + hh * 32 + 4 * j4;
            v = make_float4(p[0], p[1], p[2], p[3]);
        } else {
            const float* p = b_in + hh * 32 + 4 * (r - 48);
            v = make_float4(p[0], p[1], p[2], p[3]);
        }
        sW4[hh][r] = v;
    }

    // stage x: 256 contiguous s-rows = 384 float4
    {
        const float4* xp = (const float4*)(x + ((size_t)b * SS + (size_t)gq * 256) * DD);
        float4* sx4 = (float4*)sX;
        for (int idx = tid; idx < 384; idx += 256) sx4[idx] = xp[idx];
    }

    // stage W_out -> transposed bf16 LDS (swizzled): Wt[n][k], once per block
    // W_out is 256x32 fp32 = 2048 float4.  idx = k*8 + j4, k=0..255, cols 4*j4..+3.
    for (int idx = tid; idx < 2048; idx += 256) {
        int k = idx >> 3, n4 = (idx & 7) << 2;
        float4 w4 = ((const float4*)W_out)[idx];
        ushort_t vals[4] = { bf1(w4.x), bf1(w4.y), bf1(w4.z), bf1(w4.w) };
#pragma unroll
        for (int j = 0; j < 4; ++j) {
            int n = n4 + j;
            uint32_t off = (uint32_t)(n * 512 + 2 * k) ^ (uint32_t)((n & 7) << 4);
            *(ushort_t*)((char*)Wt + off) = vals[j];
        }
    }
    __syncthreads();                        // cross-wave: staging complete

    // carry -> p
    float p[32];
#pragma unroll
    for (int m = 0; m < 8; ++m) {
        p[4*m] = pv[m].x; p[4*m+1] = pv[m].y; p[4*m+2] = pv[m].z; p[4*m+3] = pv[m].w;
    }

    // B-fragments from Wt: B[k][n], k = kk*32 + q*8 + j, n = nt*16 + n0
    bf16x8 Bf[2][8];
#pragma unroll
    for (int nt = 0; nt < 2; ++nt) {
        int n = nt * 16 + n0;
        uint32_t rb = (uint32_t)(n * 512);
        uint32_t sw = (uint32_t)((n & 7) << 4);
#pragma unroll
        for (int kk = 0; kk < 8; ++kk)
            Bf[nt][kk] = *(const bf16x8*)((const char*)Wt + ((rb + kk * 64 + q * 16) ^ sw));
    }
    float bn0 = b_out[n0], bn1 = b_out[16 + n0];

    ushort_t* myT = psiT + wv * 16 * 256;

#pragma unroll 1
    for (int pr = 0; pr < 4; ++pr) {        // 2 steps per round
        float xv[12];
        {
            // (384*wv + 48*cl + 12*pr) floats: always a multiple of 4 -> 16B aligned
            const float* xr = sX + (wv * 64 + cl * 8 + 2 * pr) * 6;
            loadx12(xr, xv);
        }

        float dl0[32], dl1[32], o[32];
        make_delta2(sW4[h], xv, dl0, dl1);  // one W pass serves both steps

        gp_cl41(dl0, p, o);                 // step 2*pr (delta LEFT)
        {
            float inv = rsq(sumsq32(o));
            int row = cl * 2;
            uint32_t rb = (uint32_t)(row * 512 + h * 64);
            uint32_t sw = (uint32_t)((row & 7) << 4);
            uint32_t pk[16];
#pragma unroll
            for (int m = 0; m < 16; ++m)
                pk[m] = pack2bf(o[2*m] * inv, o[2*m+1] * inv);
#pragma unroll
            for (int m = 0; m < 4; ++m)
                *(uint4*)((char*)myT + ((rb + 16 * m) ^ sw)) =
                    make_uint4(pk[4*m], pk[4*m+1], pk[4*m+2], pk[4*m+3]);
        }
        gp_cl41(dl1, o, p);                 // step 2*pr+1
        {
            float inv = rsq(sumsq32(p));
            int row = cl * 2 + 1;
            uint32_t rb = (uint32_t)(row * 512 + h * 64);
            uint32_t sw = (uint32_t)((row & 7) << 4);
            uint32_t pk[16];
#pragma unroll
            for (int m = 0; m < 16; ++m)
                pk[m] = pack2bf(p[2*m] * inv, p[2*m+1] * inv);
#pragma unroll
            for (int m = 0; m < 4; ++m)
                *(uint4*)((char*)myT + ((rb + 16 * m) ^ sw)) =
                    make_uint4(pk[4*m], pk[4*m+1], pk[4*m+2], pk[4*m+3]);
        }

        // projection: 16x256 @ 256x32 via 16 MFMAs (swizzled A-reads).
        // Compiler inserts the lgkmcnt wait for the psiT RAW; setprio favors
        // the MFMA-issuing wave (waves drift out of phase: no intra-loop barriers).
        f32x4 acc0 = {0.f, 0.f, 0.f, 0.f};
        f32x4 acc1 = {0.f, 0.f, 0.f, 0.f};
        __builtin_amdgcn_s_setprio(1);
        {
            uint32_t rb = (uint32_t)(n0 * 512);
            uint32_t sw = (uint32_t)((n0 & 7) << 4);
#pragma unroll
            for (int kk = 0; kk < 8; ++kk) {
                bf16x8 af = *(const bf16x8*)((const char*)myT + ((rb + kk * 64 + q * 16) ^ sw));
                acc0 = __builtin_amdgcn_mfma_f32_16x16x32_bf16(af, Bf[0][kk], acc0, 0, 0, 0);
                acc1 = __builtin_amdgcn_mfma_f32_16x16x32_bf16(af, Bf[1][kk], acc1, 0, 0, 0);
            }
        }
        __builtin_amdgcn_s_setprio(0);

        // epilogue: bias, row-norm across 32 cols (16 lanes x 2), store
        float c0v[4], c1v[4], ssq[4];
#pragma unroll
        for (int i = 0; i < 4; ++i) {
            c0v[i] = acc0[i] + bn0;
            c1v[i] = acc1[i] + bn1;
            ssq[i] = c0v[i] * c0v[i] + c1v[i] * c1v[i];
        }
#pragma unroll
        for (int m = 1; m < 16; m <<= 1) {
#pragma unroll
            for (int i = 0; i < 4; ++i) ssq[i] += __shfl_xor(ssq[i], m);
        }
#pragma unroll
        for (int i = 0; i < 4; ++i) {
            float inv = rsq(ssq[i]);
            int mrow = q * 4 + i;           // psiT row = 2*cl' + tt
            int s = (c0 + (mrow >> 1)) * LCH + 2 * pr + (mrow & 1);
            size_t row = (size_t)b * SS + s;
            out[row * 32 + n0]      = c0v[i] * inv;
            out[row * 32 + 16 + n0] = c1v[i] * inv;
        }
    }
}

// ---------------- launcher ----------------
extern "C" void kernel_launch(void* const* d_in, const int* in_sizes, int n_in,
                              void* d_out, int out_size, void* d_ws, size_t ws_size,
                              hipStream_t stream) {
    const float* x     = (const float*)d_in[0];
    const float* W_in  = (const float*)d_in[1];
    const float* b_in  = (const float*)d_in[2];
    const float* W_out = (const float*)d_in[3];
    const float* b_out = (const float*)d_in[4];
    float* out = (float*)d_out;

    float* Ebuf = (float*)d_ws;   // 512*256*32*4 = 16.78 MB carries (fp32)

    k_scan      <<<NCH, 256, 0, stream>>>(x, W_in, b_in, Ebuf);
    k_chain_proj<<<NCH, 256, 0, stream>>>(x, W_in, b_in, Ebuf, W_out, b_out, out);
}

// Round 14
// 162.902 us; speedup vs baseline: 1.0292x; 1.0292x over previous
//
#include <hip/hip_runtime.h>
#include <hip/hip_bf16.h>
#include <stdint.h>

// Problem constants (from reference setup_inputs)
#define BB 64
#define SS 2048
#define DD 6
#define HH 8
#define NCH 512           // chains = B*H
#define CHUNKS 256        // chunks per chain
#define LCH 8             // steps per chunk = SS/CHUNKS

typedef unsigned short ushort_t;
typedef __attribute__((ext_vector_type(8))) __bf16 bf16x8;
typedef __attribute__((ext_vector_type(4))) float f32x4;

// ---------------- compile-time Cayley sign table (Cl(4,1)) ----------------
struct SignTab { float s[32][32]; };

constexpr int popc5_c(unsigned v) {
    int c = 0;
    for (int i = 0; i < 5; ++i) c += (v >> i) & 1u;
    return c;
}

constexpr SignTab make_signs() {
    SignTab t{};
    for (int a = 0; a < 32; ++a) {
        for (int b = 0; b < 32; ++b) {
            int cnt = 0;
            unsigned aa = ((unsigned)a) >> 1;
            while (aa) { cnt += popc5_c(aa & (unsigned)b); aa >>= 1; }
            if ((a & b) & 16) cnt += 1;   // metric: e5^2 = -1 (bit 4)
            t.s[a][b] = (cnt & 1) ? -1.0f : 1.0f;
        }
    }
    return t;
}

constexpr SignTab SGN = make_signs();

// out = a * b  (geometric product, a is LEFT operand: out_k = sum_i s(i,i^k) a_i b_{i^k})
__device__ __forceinline__ void gp_cl41(const float* __restrict__ a,
                                        const float* __restrict__ b,
                                        float* __restrict__ o) {
#pragma unroll
    for (int k = 0; k < 32; ++k) o[k] = 0.0f;
#pragma unroll
    for (int i = 0; i < 32; ++i) {
#pragma unroll
        for (int k = 0; k < 32; ++k) {
            o[k] = fmaf(SGN.s[i][i ^ k] * a[i], b[i ^ k], o[k]);
        }
    }
}

__device__ __forceinline__ float sumsq32(const float* v) {
    float n0 = 0.f, n1 = 0.f, n2 = 0.f, n3 = 0.f;
#pragma unroll
    for (int k = 0; k < 32; k += 4) {
        n0 = fmaf(v[k+0], v[k+0], n0);
        n1 = fmaf(v[k+1], v[k+1], n1);
        n2 = fmaf(v[k+2], v[k+2], n2);
        n3 = fmaf(v[k+3], v[k+3], n3);
    }
    return (n0 + n1) + (n2 + n3);
}

__device__ __forceinline__ float rsq(float n) {
    return __builtin_amdgcn_rsqf(n);   // v_rsq_f32, scale-equivalent
}

// HW bf16 pack: (__bf16) casts are RNE on gfx950; compiler emits
// v_cvt_pk_bf16_f32 for the pair (round-10 win vs bit-math).
__device__ __forceinline__ uint32_t pack2bf(float a, float b) {
    union { __bf16 h[2]; uint32_t u; } t;
    t.h[0] = (__bf16)a; t.h[1] = (__bf16)b;
    return t.u;
}
__device__ __forceinline__ ushort_t bf1(float a) {
    union { __bf16 h; ushort_t u; } t;
    t.h = (__bf16)a;
    return t.u;
}

// SCALARIZED delta build — k_scan only. All lanes share one h, so every
// W_in/b_in address is WAVE-UNIFORM: with __restrict__ and blockIdx-derived h,
// the compiler emits s_load through the scalar cache. This removes the 448
// ds_read_b128 broadcast stream (and its lgkm dependency stalls) from phase 1;
// FMAs take SGPR operands directly (v_fma dst, s, v — 1 SGPR read, legal).
__device__ __forceinline__ void make_delta1g(const float* __restrict__ Wb,   // W_in + h*32
                                             const float* __restrict__ bb,   // b_in + h*32
                                             const float* __restrict__ x6,
                                             float* __restrict__ dl) {
#pragma unroll
    for (int j = 0; j < 32; ++j) dl[j] = bb[j];
#pragma unroll
    for (int d = 0; d < 6; ++d) {
        float a = x6[d];
#pragma unroll
        for (int j = 0; j < 32; ++j)
            dl[j] = fmaf(a, Wb[d * 256 + j], dl[j]);
    }
    dl[0] += 1.0f;
}

// PAIRED delta build — k_chain only (per-lane h differs; pairing halves REAL
// LDS traffic there).
__device__ __forceinline__ void make_delta2(const float4* __restrict__ sW,
                                            const float* __restrict__ xv,
                                            float* __restrict__ dl0,
                                            float* __restrict__ dl1) {
#pragma unroll
    for (int j4 = 0; j4 < 8; ++j4) {
        float4 bv = sW[48 + j4];
        dl0[4*j4+0] = bv.x; dl0[4*j4+1] = bv.y; dl0[4*j4+2] = bv.z; dl0[4*j4+3] = bv.w;
        dl1[4*j4+0] = bv.x; dl1[4*j4+1] = bv.y; dl1[4*j4+2] = bv.z; dl1[4*j4+3] = bv.w;
    }
#pragma unroll
    for (int d = 0; d < 6; ++d) {
        float a0 = xv[d], a1 = xv[6 + d];
#pragma unroll
        for (int j4 = 0; j4 < 8; ++j4) {
            float4 w = sW[d * 8 + j4];
            dl0[4*j4+0] = fmaf(a0, w.x, dl0[4*j4+0]);
            dl0[4*j4+1] = fmaf(a0, w.y, dl0[4*j4+1]);
            dl0[4*j4+2] = fmaf(a0, w.z, dl0[4*j4+2]);
            dl0[4*j4+3] = fmaf(a0, w.w, dl0[4*j4+3]);
            dl1[4*j4+0] = fmaf(a1, w.x, dl1[4*j4+0]);
            dl1[4*j4+1] = fmaf(a1, w.y, dl1[4*j4+1]);
            dl1[4*j4+2] = fmaf(a1, w.z, dl1[4*j4+2]);
            dl1[4*j4+3] = fmaf(a1, w.w, dl1[4*j4+3]);
        }
    }
    dl0[0] += 1.0f;
    dl1[0] += 1.0f;
}

__device__ __forceinline__ void loadx6(const float* __restrict__ xr, float* __restrict__ xv) {
    const float2* xp = (const float2*)xr;   // 24B-multiple offsets -> 8B aligned
#pragma unroll
    for (int m = 0; m < 3; ++m) {
        float2 t2 = xp[m];
        xv[2*m] = t2.x; xv[2*m+1] = t2.y;
    }
}

__device__ __forceinline__ void loadx12(const float* __restrict__ xr, float* __restrict__ xv) {
    const float4* xp = (const float4*)xr;
#pragma unroll
    for (int m = 0; m < 3; ++m) {
        float4 t4 = xp[m];
        xv[4*m] = t4.x; xv[4*m+1] = t4.y; xv[4*m+2] = t4.z; xv[4*m+3] = t4.w;
    }
}

// ---------------- K_A: fused chunk totals + Kogge-Stone scan -> carries ----------------
// Round-13 body (65.7us, FETCH 1.7MB) with phase-1 W reads SCALARIZED:
// no sW4 LDS staging, no staging barrier; make_delta1g reads W_in/b_in at
// wave-uniform addresses -> s_load/SGPR operands; DS pipe free in phase 1.
//  - XCD-aware chain remap kept (round 13: FETCH 12.5 -> 1.7MB).
//  - one-ahead x prefetch kept (named regs, rule #20).
// Round-8 lesson: forced VGPR caps spill catastrophically -> (256,1) only.
// Round-9 lesson: no fusion with phase 2 (cross-XCD L2 non-coherence on Ebuf).
__global__ __launch_bounds__(256, 1) void k_scan(
        const float* __restrict__ x, const float* __restrict__ W_in,
        const float* __restrict__ b_in, float* __restrict__ Ebuf) {
    __shared__ float sT[2][CHUNKS][36]; // 72 KB double-buffered scan array

    // XCD-aware remap (bijective over 512)
    int xcd  = blockIdx.x & 7;
    int slot = blockIdx.x >> 3;         // 0..63
    int b = (xcd << 3) | (slot >> 3);   // all 8 h of this b share xcd
    int h = slot & 7;
    int chain = b * 8 + h;              // logical chain for Ebuf addressing
    int c = threadIdx.x;                // chunk 0..255

    const float* Wb = W_in + h * 32;    // wave-uniform base -> scalar loads
    const float* bb = b_in + h * 32;

    // ---- phase 1: chunk total, ONE textual GP, one-ahead x prefetch ----
    const float* xrow = x + ((size_t)b * SS + (size_t)c * LCH) * DD;  // 48 floats
    float P[32], O[32], dl[32];
    float xc[6], xn[6];
    loadx6(xrow, xc);
    make_delta1g(Wb, bb, xc, P);         // psi after t=0 == delta0 (GP folded)
    loadx6(xrow + 6, xc);                // x for t=1
#pragma unroll 1
    for (int t = 1; t < 8; ++t) {
        if (t < 7) loadx6(xrow + 6 * (t + 1), xn);   // prefetch next step
        make_delta1g(Wb, bb, xc, dl);
        gp_cl41(dl, P, O);               // textual GP copy #1
#pragma unroll
        for (int k = 0; k < 32; ++k) P[k] = O[k];
#pragma unroll
        for (int d = 0; d < 6; ++d) xc[d] = xn[d];
    }

    // normalized chunk total -> v, sT[0]
    float v[32];
    {
        float inv = rsq(sumsq32(P));
#pragma unroll
        for (int k = 0; k < 32; ++k) v[k] = P[k] * inv;
#pragma unroll
        for (int m = 0; m < 8; ++m)
            *(float4*)&sT[0][c][4*m] = make_float4(v[4*m], v[4*m+1], v[4*m+2], v[4*m+3]);
    }
    __syncthreads();

    // ---- phase 2: merged KS rounds rr=0..7 (off=1..128), ONE textual GP ----
    // Double-buffered: read sT[rr&1][c-off], write sT[(rr+1)&1][c] (ALL threads
    // store: propagation). Final round (rr=7): no store, no barrier.
    // Norm every other round (positive rescale -> scale-equivalent).
#pragma unroll 1
    for (int rr = 0; rr < 8; ++rr) {
        int off = 1 << rr;
        bool act = (c >= off);
        if (act) {
            float w[32];
#pragma unroll
            for (int m = 0; m < 8; ++m) {
                float4 t4 = *(const float4*)&sT[rr & 1][c - off][4*m];
                w[4*m] = t4.x; w[4*m+1] = t4.y; w[4*m+2] = t4.z; w[4*m+3] = t4.w;
            }
            gp_cl41(v, w, O);            // textual GP copy #2 (v newer -> left)
            if (rr & 1) {
                float inv = rsq(sumsq32(O));
#pragma unroll
                for (int k = 0; k < 32; ++k) v[k] = O[k] * inv;
            } else {
#pragma unroll
                for (int k = 0; k < 32; ++k) v[k] = O[k];
            }
        }
        if (rr < 7) {
#pragma unroll
            for (int m = 0; m < 8; ++m)
                *(float4*)&sT[(rr + 1) & 1][c][4*m] =
                    make_float4(v[4*m], v[4*m+1], v[4*m+2], v[4*m+3]);
            __syncthreads();
        }
    }

    // exclusive carries: E_0 = identity, E_{c+1} = normalize(inclusive_c)
    float* dst = Ebuf + (size_t)chain * CHUNKS * 32;
    if (c == 0) {
        *(float4*)dst = make_float4(1.f, 0.f, 0.f, 0.f);
#pragma unroll
        for (int m = 1; m < 8; ++m) *(float4*)(dst + 4*m) = make_float4(0.f, 0.f, 0.f, 0.f);
    }
    if (c < CHUNKS - 1) {
        float inv = rsq(sumsq32(v));
        float* d2 = dst + (size_t)(c + 1) * 32;
#pragma unroll
        for (int m = 0; m < 8; ++m)
            *(float4*)(d2 + 4*m) = make_float4(v[4*m] * inv, v[4*m+1] * inv,
                                               v[4*m+2] * inv, v[4*m+3] * inv);
    }
}

// ---------------- K_B: chain-from-carry + MFMA projection + norm ----------------
// (FROZEN round-10 body: fence-free wave-private psiT, setprio around MFMA,
// HW v_cvt_pk_bf16_f32 packs. h varies per lane -> cannot scalarize W here.)
__global__ __launch_bounds__(256, 1) void k_chain_proj(
        const float* __restrict__ x, const float* __restrict__ W_in,
        const float* __restrict__ b_in, const float* __restrict__ Ebuf,
        const float* __restrict__ W_out, const float* __restrict__ b_out,
        float* __restrict__ out) {
    __shared__ float4 sW4[8][57];           // 7.3 KB  W_in slices + bias
    __shared__ float sX[1536];              // 6 KB    256 s-rows x 6 floats
    __shared__ ushort_t Wt[32 * 256];       // 16 KB   W_out^T bf16, swizzled [n][k]
    __shared__ ushort_t psiT[4 * 16 * 256]; // 32 KB   per-wave 16x256 tiles, swizzled

    int tid = threadIdx.x;
    int wv = tid >> 6, lane = tid & 63;
    int b = blockIdx.x >> 3, gq = blockIdx.x & 7;
    int grp = gq * 4 + wv;
    int c0 = grp * 8;
    int cl = lane >> 3, h = lane & 7;       // chain-phase roles
    int q = lane >> 4, n0 = lane & 15;      // MFMA-phase roles

    // carry load early (hide HBM latency under staging)
    float4 pv[8];
    {
        const float4* ep = (const float4*)(Ebuf +
                (((size_t)b * HH + h) * CHUNKS + (c0 + cl)) * 32);
#pragma unroll
        for (int m = 0; m < 8; ++m) pv[m] = ep[m];
    }

    // stage W_in/b_in (448 float4, shared by all 4 waves)
    for (int idx = tid; idx < 448; idx += 256) {
        int hh = idx / 56, r = idx % 56;
        float4 v;
        if (r < 48) {
            int d = r / 8, j4 = r % 8;
            const float* p = W_in + d * 256 + hh * 32 + 4 * j4;
            v = make_float4(p[0], p[1], p[2], p[3]);
        } else {
            const float* p = b_in + hh * 32 + 4 * (r - 48);
            v = make_float4(p[0], p[1], p[2], p[3]);
        }
        sW4[hh][r] = v;
    }

    // stage x: 256 contiguous s-rows = 384 float4
    {
        const float4* xp = (const float4*)(x + ((size_t)b * SS + (size_t)gq * 256) * DD);
        float4* sx4 = (float4*)sX;
        for (int idx = tid; idx < 384; idx += 256) sx4[idx] = xp[idx];
    }

    // stage W_out -> transposed bf16 LDS (swizzled): Wt[n][k], once per block
    // W_out is 256x32 fp32 = 2048 float4.  idx = k*8 + j4, k=0..255, cols 4*j4..+3.
    for (int idx = tid; idx < 2048; idx += 256) {
        int k = idx >> 3, n4 = (idx & 7) << 2;
        float4 w4 = ((const float4*)W_out)[idx];
        ushort_t vals[4] = { bf1(w4.x), bf1(w4.y), bf1(w4.z), bf1(w4.w) };
#pragma unroll
        for (int j = 0; j < 4; ++j) {
            int n = n4 + j;
            uint32_t off = (uint32_t)(n * 512 + 2 * k) ^ (uint32_t)((n & 7) << 4);
            *(ushort_t*)((char*)Wt + off) = vals[j];
        }
    }
    __syncthreads();                        // cross-wave: staging complete

    // carry -> p
    float p[32];
#pragma unroll
    for (int m = 0; m < 8; ++m) {
        p[4*m] = pv[m].x; p[4*m+1] = pv[m].y; p[4*m+2] = pv[m].z; p[4*m+3] = pv[m].w;
    }

    // B-fragments from Wt: B[k][n], k = kk*32 + q*8 + j, n = nt*16 + n0
    bf16x8 Bf[2][8];
#pragma unroll
    for (int nt = 0; nt < 2; ++nt) {
        int n = nt * 16 + n0;
        uint32_t rb = (uint32_t)(n * 512);
        uint32_t sw = (uint32_t)((n & 7) << 4);
#pragma unroll
        for (int kk = 0; kk < 8; ++kk)
            Bf[nt][kk] = *(const bf16x8*)((const char*)Wt + ((rb + kk * 64 + q * 16) ^ sw));
    }
    float bn0 = b_out[n0], bn1 = b_out[16 + n0];

    ushort_t* myT = psiT + wv * 16 * 256;

#pragma unroll 1
    for (int pr = 0; pr < 4; ++pr) {        // 2 steps per round
        float xv[12];
        {
            // (384*wv + 48*cl + 12*pr) floats: always a multiple of 4 -> 16B aligned
            const float* xr = sX + (wv * 64 + cl * 8 + 2 * pr) * 6;
            loadx12(xr, xv);
        }

        float dl0[32], dl1[32], o[32];
        make_delta2(sW4[h], xv, dl0, dl1);  // one W pass serves both steps

        gp_cl41(dl0, p, o);                 // step 2*pr (delta LEFT)
        {
            float inv = rsq(sumsq32(o));
            int row = cl * 2;
            uint32_t rb = (uint32_t)(row * 512 + h * 64);
            uint32_t sw = (uint32_t)((row & 7) << 4);
            uint32_t pk[16];
#pragma unroll
            for (int m = 0; m < 16; ++m)
                pk[m] = pack2bf(o[2*m] * inv, o[2*m+1] * inv);
#pragma unroll
            for (int m = 0; m < 4; ++m)
                *(uint4*)((char*)myT + ((rb + 16 * m) ^ sw)) =
                    make_uint4(pk[4*m], pk[4*m+1], pk[4*m+2], pk[4*m+3]);
        }
        gp_cl41(dl1, o, p);                 // step 2*pr+1
        {
            float inv = rsq(sumsq32(p));
            int row = cl * 2 + 1;
            uint32_t rb = (uint32_t)(row * 512 + h * 64);
            uint32_t sw = (uint32_t)((row & 7) << 4);
            uint32_t pk[16];
#pragma unroll
            for (int m = 0; m < 16; ++m)
                pk[m] = pack2bf(p[2*m] * inv, p[2*m+1] * inv);
#pragma unroll
            for (int m = 0; m < 4; ++m)
                *(uint4*)((char*)myT + ((rb + 16 * m) ^ sw)) =
                    make_uint4(pk[4*m], pk[4*m+1], pk[4*m+2], pk[4*m+3]);
        }

        // projection: 16x256 @ 256x32 via 16 MFMAs (swizzled A-reads).
        // Compiler inserts the lgkmcnt wait for the psiT RAW; setprio favors
        // the MFMA-issuing wave (waves drift out of phase: no intra-loop barriers).
        f32x4 acc0 = {0.f, 0.f, 0.f, 0.f};
        f32x4 acc1 = {0.f, 0.f, 0.f, 0.f};
        __builtin_amdgcn_s_setprio(1);
        {
            uint32_t rb = (uint32_t)(n0 * 512);
            uint32_t sw = (uint32_t)((n0 & 7) << 4);
#pragma unroll
            for (int kk = 0; kk < 8; ++kk) {
                bf16x8 af = *(const bf16x8*)((const char*)myT + ((rb + kk * 64 + q * 16) ^ sw));
                acc0 = __builtin_amdgcn_mfma_f32_16x16x32_bf16(af, Bf[0][kk], acc0, 0, 0, 0);
                acc1 = __builtin_amdgcn_mfma_f32_16x16x32_bf16(af, Bf[1][kk], acc1, 0, 0, 0);
            }
        }
        __builtin_amdgcn_s_setprio(0);

        // epilogue: bias, row-norm across 32 cols (16 lanes x 2), store
        float c0v[4], c1v[4], ssq[4];
#pragma unroll
        for (int i = 0; i < 4; ++i) {
            c0v[i] = acc0[i] + bn0;
            c1v[i] = acc1[i] + bn1;
            ssq[i] = c0v[i] * c0v[i] + c1v[i] * c1v[i];
        }
#pragma unroll
        for (int m = 1; m < 16; m <<= 1) {
#pragma unroll
            for (int i = 0; i < 4; ++i) ssq[i] += __shfl_xor(ssq[i], m);
        }
#pragma unroll
        for (int i = 0; i < 4; ++i) {
            float inv = rsq(ssq[i]);
            int mrow = q * 4 + i;           // psiT row = 2*cl' + tt
            int s = (c0 + (mrow >> 1)) * LCH + 2 * pr + (mrow & 1);
            size_t row = (size_t)b * SS + s;
            out[row * 32 + n0]      = c0v[i] * inv;
            out[row * 32 + 16 + n0] = c1v[i] * inv;
        }
    }
}

// ---------------- launcher ----------------
extern "C" void kernel_launch(void* const* d_in, const int* in_sizes, int n_in,
                              void* d_out, int out_size, void* d_ws, size_t ws_size,
                              hipStream_t stream) {
    const float* x     = (const float*)d_in[0];
    const float* W_in  = (const float*)d_in[1];
    const float* b_in  = (const float*)d_in[2];
    const float* W_out = (const float*)d_in[3];
    const float* b_out = (const float*)d_in[4];
    float* out = (float*)d_out;

    float* Ebuf = (float*)d_ws;   // 512*256*32*4 = 16.78 MB carries (fp32)

    k_scan      <<<NCH, 256, 0, stream>>>(x, W_in, b_in, Ebuf);
    k_chain_proj<<<NCH, 256, 0, stream>>>(x, W_in, b_in, Ebuf, W_out, b_out, out);
}